// Round 13
// baseline (671.840 us; speedup 1.0000x reference)
//
#include <hip/hip_runtime.h>
#include <hip/hip_bf16.h>
#include <math.h>

// B=4096 queries, D=256, K=65536 centroids (f32).
// Round 13: round-12 scan (transposed MFMA, validated) + cf k-prefetch double-buffer;
// tail de-serialized: emit writes per-query candidate lists (distributed atomics),
// rescore+final fused into one atomic-free wave-per-query kernel (in-register fkey min).
// Margin/comparator/grouping identical to validated rounds 9-12.

#define DDIM 256
#define QTILE 128
#define STSZ 8192      // centroids per strip (8 strips)
#define QCAP 48        // candidate groups per query
#define F16_MINN 6.103515625e-5f

typedef __attribute__((ext_vector_type(8))) _Float16 half8;
typedef __attribute__((ext_vector_type(4))) _Float16 half4;
typedef __attribute__((ext_vector_type(4))) float f32x4;

__device__ __forceinline__ void gl_lds16(const void* g, void* l) {
  __builtin_amdgcn_global_load_lds((const __attribute__((address_space(1))) void*)g,
                                   (__attribute__((address_space(3))) void*)l, 16, 0, 0);
}

// exact order-preserving float -> uint key (finite floats; matches f32 <)
__device__ __forceinline__ unsigned fkey(float d) {
  unsigned ud = __float_as_uint(d);
  return ud ^ (((int)ud < 0) ? 0xFFFFFFFFu : 0x80000000u);
}

// ---------------- ctl init: [32]=cmax_sq bits ----------------
__global__ void initctl_kernel(unsigned* __restrict__ ctl) {
  if (threadIdx.x < 64) ctl[threadIdx.x] = 0u;
}

// ---------------- centroid split + c_sq fused (one wave = one 256-elem row) --------
__global__ __launch_bounds__(256) void splitc_kernel(const float* __restrict__ in,
                                                     _Float16* __restrict__ o0,
                                                     float* __restrict__ c_sq) {
  int i = blockIdx.x * 256 + threadIdx.x;   // 4-elem chunk id; wave = one row
  int lane = (int)threadIdx.x & 63;
  float4 v = ((const float4*)in)[i];
  float vv[4] = {v.x, v.y, v.z, v.w};
  half4 h0;
#pragma unroll
  for (int e = 0; e < 4; ++e)
    h0[e] = (fabsf(vv[e]) < F16_MINN) ? (_Float16)0.f : (_Float16)vv[e];
  *(half4*)(o0 + (size_t)i * 4) = h0;
  float s = fmaf(v.x, v.x, fmaf(v.y, v.y, fmaf(v.z, v.z, v.w * v.w)));
#pragma unroll
  for (int off = 32; off > 0; off >>= 1) s += __shfl_down(s, off, 64);
  if (lane == 0) c_sq[i >> 6] = s;
}

// ---------------- x split: hi part only ----------------
__global__ __launch_bounds__(256) void splitx_kernel(const float* __restrict__ in,
                                                     _Float16* __restrict__ o0, int n4) {
  int i = blockIdx.x * 256 + threadIdx.x;
  if (i >= n4) return;
  float4 v = ((const float4*)in)[i];
  float vv[4] = {v.x, v.y, v.z, v.w};
  half4 h0;
#pragma unroll
  for (int e = 0; e < 4; ++e)
    h0[e] = (fabsf(vv[e]) < F16_MINN) ? (_Float16)0.f : (_Float16)vv[e];
  *(half4*)(o0 + (size_t)i * 4) = h0;
}

// ---------------- cmax: 2-stage max of c_sq, one atomic per block (64 total) --------
__global__ __launch_bounds__(256) void cmax_kernel(const float* __restrict__ c_sq,
                                                   unsigned* __restrict__ ctl) {
  __shared__ float red[4];
  int t = blockIdx.x * 256 + (int)threadIdx.x;
  float4 v = ((const float4*)c_sq)[t];
  float m = fmaxf(fmaxf(v.x, v.y), fmaxf(v.z, v.w));
#pragma unroll
  for (int off = 32; off > 0; off >>= 1) m = fmaxf(m, __shfl_down(m, off, 64));
  int lane = (int)threadIdx.x & 63, w = (int)threadIdx.x >> 6;
  if (lane == 0) red[w] = m;
  __syncthreads();
  if (threadIdx.x == 0) {
    m = fmaxf(fmaxf(red[0], red[1]), fmaxf(red[2], red[3]));
    atomicMax(&ctl[32], __float_as_uint(m));
  }
}

// ---------------- scan: 1-term f16 MFMA (centroids=M rows), min per (q,32c-group) ----
// Round-12 validated structure + cf double-buffer prefetch across kt.
__global__ __launch_bounds__(512, 2) void scan_kernel(
    const _Float16* __restrict__ x0, const _Float16* __restrict__ c0,
    const float* __restrict__ c_sq, float* __restrict__ dm) {
  __shared__ __align__(16) _Float16 As0[32768];   // 64 KiB

  const int qb = blockIdx.x, kc = blockIdx.y;
  const int tid = (int)threadIdx.x;
  const int lane = tid & 63, w = tid >> 6;
  const int col = lane & 15, quad = lane >> 4;
  const int qrow0 = qb * QTILE;

#pragma unroll
  for (int i = 0; i < 8; ++i) {
    int u = i * 512 + tid;                 // 0..4095 (16B chunks)
    int kt = u >> 9, q = (u >> 7) & 3, r = u & 127;
    gl_lds16(x0 + (size_t)(qrow0 + r) * DDIM + kt * 32 + q * 8, As0 + (size_t)u * 8);
  }
  __syncthreads();   // only barrier

  for (int ct = 0; ct < STSZ / 512; ++ct) {
    const int cbase = kc * STSZ + ct * 512 + w * 64;   // wave-private 64-c slice
    const _Float16* pw = c0 + (size_t)(cbase + col) * DDIM + quad * 8;
    f32x4 acc[4][8];                                    // [cm][qn]
#pragma unroll
    for (int cm = 0; cm < 4; ++cm)
#pragma unroll
      for (int qn = 0; qn < 8; ++qn) acc[cm][qn] = (f32x4)0.0f;

    half8 cf[2][4];
#pragma unroll
    for (int cm = 0; cm < 4; ++cm) cf[0][cm] = *(const half8*)(pw + cm * 16 * DDIM);

#pragma unroll
    for (int kt = 0; kt < 8; ++kt) {
      const int cur = kt & 1, nxt = cur ^ 1;
      const int kn = ((kt + 1) & 7) * 32;   // wrap prefetch (kt=7 reloads kt=0: L1-hit)
#pragma unroll
      for (int cm = 0; cm < 4; ++cm)
        cf[nxt][cm] = *(const half8*)(pw + cm * 16 * DDIM + kn);
#pragma unroll
      for (int qn = 0; qn < 8; ++qn) {
        half8 qf = *(const half8*)(As0 + (((kt * 4 + quad) * QTILE) + qn * 16 + col) * 8);
#pragma unroll
        for (int cm = 0; cm < 4; ++cm)
          acc[cm][qn] = __builtin_amdgcn_mfma_f32_16x16x32_f16(cf[cur][cm], qf, acc[cm][qn], 0, 0, 0);
      }
    }

    // epilogue: d = cs - 2*dot; min over 32 centroids (2 cm-tiles: in-lane rg + quad xor)
    f32x4 csv[4];
#pragma unroll
    for (int cm = 0; cm < 4; ++cm)
      csv[cm] = *(const f32x4*)(c_sq + cbase + cm * 16 + quad * 4);
#pragma unroll
    for (int h = 0; h < 2; ++h) {
      const int grp = kc * 256 + ct * 16 + w * 2 + h;
      float* dmg = dm + (size_t)grp * 4096 + qrow0;
#pragma unroll
      for (int qn = 0; qn < 8; ++qn) {
        float mq = INFINITY;
#pragma unroll
        for (int c2 = 0; c2 < 2; ++c2) {
          int cm = h * 2 + c2;
#pragma unroll
          for (int rg = 0; rg < 4; ++rg)
            mq = fminf(mq, fmaf(-2.0f, acc[cm][qn][rg], csv[cm][rg]));
        }
        mq = fminf(mq, __shfl_xor(mq, 16, 64));
        mq = fminf(mq, __shfl_xor(mq, 32, 64));
        if (quad == 0) dmg[qn * 16 + col] = mq;         // 16 lanes, 64 B dense
      }
    }
  }
}

// ---------------- pmin: partial column-min of dm ----------------
__global__ __launch_bounds__(256) void pmin_kernel(const float* __restrict__ dm,
                                                   float* __restrict__ pm) {
  int qc = blockIdx.x & 15, gc = blockIdx.x >> 4;
  int q = qc * 256 + (int)threadIdx.x;
  float m = INFINITY;
  for (int g = gc * 128; g < gc * 128 + 128; ++g)
    m = fminf(m, dm[(size_t)g * 4096 + q]);
  pm[gc * 4096 + q] = m;
}

// ---------------- tq: per-query threshold + cnt zero ----------------
__global__ __launch_bounds__(256) void tq_kernel(const float* __restrict__ pm,
                                                 const float* __restrict__ x,
                                                 const unsigned* __restrict__ ctl,
                                                 float* __restrict__ T,
                                                 unsigned* __restrict__ cnt) {
  int q = blockIdx.x * 256 + (int)threadIdx.x;
  float M = INFINITY;
#pragma unroll
  for (int i = 0; i < 16; ++i) M = fminf(M, pm[i * 4096 + q]);
  float xsq = 0.f;
  const float4* xr = (const float4*)(x + (size_t)q * DDIM);
#pragma unroll 8
  for (int i = 0; i < 64; ++i) {
    float4 v = xr[i];
    xsq = fmaf(v.x, v.x, fmaf(v.y, v.y, fmaf(v.z, v.z, fmaf(v.w, v.w, xsq))));
  }
  float cmaxsq = __uint_as_float(ctl[32]);
  // rigorous 1-term f16 bound ~2^-9 ||x|| ||c||max; margin = 4x bound + 1.0 slack
  T[q] = M + 0.0078125f * sqrtf(xsq * cmaxsq) + 1.0f;
  cnt[q] = 0u;
}

// ---------------- emit: per-query candidate group lists (distributed atomics) --------
__global__ __launch_bounds__(256) void emit_kernel(const float* __restrict__ dm,
                                                   const float* __restrict__ T,
                                                   unsigned short* __restrict__ cand,
                                                   unsigned* __restrict__ cnt) {
  int qc = blockIdx.x & 15, gc = blockIdx.x >> 4;
  int q = qc * 256 + (int)threadIdx.x;
  float t = T[q];
  for (int g = gc * 128; g < gc * 128 + 128; ++g)
    if (dm[(size_t)g * 4096 + q] <= t) {
      unsigned slot = atomicAdd(&cnt[q], 1u);   // 4096 distinct counters, ~2 ops each
      if (slot < QCAP) cand[(size_t)q * QCAP + slot] = (unsigned short)g;
    }
}

// ---------------- rescore+final: wave per query, atomic-free ----------------
__global__ __launch_bounds__(256) void rescore_final_kernel(
    const unsigned short* __restrict__ cand, const unsigned* __restrict__ cnt,
    const float* __restrict__ x, const float* __restrict__ cent,
    const float* __restrict__ c_sq, float* __restrict__ out) {
  int q = blockIdx.x * 4 + ((int)threadIdx.x >> 6);
  int lane = (int)threadIdx.x & 63;
  unsigned n = cnt[q];
  unsigned long long best = 0xFFFFFFFFFFFFFFFFull;
  if (n >= 1 && n <= QCAP) {
    int dh = (lane & 1) * 128;
    const float4* xr = (const float4*)(x + (size_t)q * DDIM + dh);
    for (unsigned sl = 0; sl < n; ++sl) {
      int g = (int)cand[(size_t)q * QCAP + sl];
      int c = g * 32 + (lane >> 1);
      const float4* cr = (const float4*)(cent + (size_t)c * DDIM + dh);
      float s = 0.f;
#pragma unroll
      for (int i = 0; i < 32; ++i) {
        float4 a = xr[i], bb = cr[i];
        s = fmaf(a.x, bb.x, fmaf(a.y, bb.y, fmaf(a.z, bb.z, fmaf(a.w, bb.w, s))));
      }
      s += __shfl_xor(s, 1, 64);
      float d = (lane & 1) ? INFINITY : fmaf(-2.0f, s, c_sq[c]);
      unsigned long long pkv = ((unsigned long long)fkey(d) << 32) | (unsigned)c;
      if (pkv < best) best = pkv;
    }
  } else {
    // safety net: exact argmin over all 65536 (overflow / empty; should never trigger)
    const float4* xr = (const float4*)(x + (size_t)q * DDIM);
    for (int c = lane; c < 65536; c += 64) {
      const float4* cr = (const float4*)(cent + (size_t)c * DDIM);
      float s = 0.f;
#pragma unroll 16
      for (int i = 0; i < 64; ++i) {
        float4 a = xr[i], bb = cr[i];
        s = fmaf(a.x, bb.x, fmaf(a.y, bb.y, fmaf(a.z, bb.z, fmaf(a.w, bb.w, s))));
      }
      float d = fmaf(-2.0f, s, c_sq[c]);
      unsigned long long pkv = ((unsigned long long)fkey(d) << 32) | (unsigned)c;
      if (pkv < best) best = pkv;
    }
  }
#pragma unroll
  for (int off = 1; off < 64; off <<= 1) {
    unsigned long long o = __shfl_xor(best, off, 64);
    if (o < best) best = o;
  }
  int idx = (int)(unsigned)(best & 0xFFFFFFFFu);
  float4 v = ((const float4*)cent)[(size_t)idx * 64 + lane];
  ((float4*)out)[(size_t)q * 64 + lane] = v;
  if (lane == 0) out[(size_t)4096 * DDIM + q] = (float)idx;
}

extern "C" void kernel_launch(void* const* d_in, const int* in_sizes, int n_in,
                              void* d_out, int out_size, void* d_ws, size_t ws_size,
                              hipStream_t stream) {
  const float* x    = (const float*)d_in[1];   // [4096,256]
  const float* cent = (const float*)d_in[2];   // [65536,256]
  float* out = (float*)d_out;
  char* ws = (char*)d_ws;

  const size_t OFF_C0   = 0;           // 33,554,432  f16 hi(centroids)
  const size_t OFF_X0   = 33554432;    //  2,097,152  f16 hi(x)
  const size_t OFF_CSQ  = 35651584;    //    262,144
  const size_t OFF_CTL  = 35913728;    //        256
  const size_t OFF_DM   = 35913984;    // 33,554,432  f32[2048][4096]
  const size_t OFF_PM   = 69468416;    //    262,144  f32[16][4096]
  const size_t OFF_T    = 69730560;    //     16,384
  const size_t OFF_CNT  = 69746944;    //     16,384  u32[4096]
  const size_t OFF_CAND = 69763328;    //    393,216  u16[4096][48]
  const size_t NEED     = 72089600;    // proven available since round 2
  if (ws_size < NEED) return;

  _Float16* c0 = (_Float16*)(ws + OFF_C0);
  _Float16* x0 = (_Float16*)(ws + OFF_X0);
  float* c_sq = (float*)(ws + OFF_CSQ);
  unsigned* ctl = (unsigned*)(ws + OFF_CTL);
  float* dm = (float*)(ws + OFF_DM);
  float* pm = (float*)(ws + OFF_PM);
  float* T  = (float*)(ws + OFF_T);
  unsigned* cnt = (unsigned*)(ws + OFF_CNT);
  unsigned short* cand = (unsigned short*)(ws + OFF_CAND);

  initctl_kernel<<<1, 64, 0, stream>>>(ctl);
  splitc_kernel<<<16384, 256, 0, stream>>>(cent, c0, c_sq);
  splitx_kernel<<<1024, 256, 0, stream>>>(x, x0, 4096 * 256 / 4);
  cmax_kernel<<<64, 256, 0, stream>>>(c_sq, ctl);
  scan_kernel<<<dim3(32, 8), 512, 0, stream>>>(x0, c0, c_sq, dm);
  pmin_kernel<<<256, 256, 0, stream>>>(dm, pm);
  tq_kernel<<<16, 256, 0, stream>>>(pm, x, ctl, T, cnt);
  emit_kernel<<<256, 256, 0, stream>>>(dm, T, cand, cnt);
  rescore_final_kernel<<<1024, 256, 0, stream>>>(cand, cnt, x, cent, c_sq, out);
}

// Round 14
// 395.676 us; speedup vs baseline: 1.6980x; 1.6980x over previous
//
#include <hip/hip_runtime.h>
#include <hip/hip_bf16.h>
#include <math.h>

// B=4096 queries, D=256, K=65536 centroids (f32).
// Round 14: recombination of proven parts. Scan = round-12 verbatim (no cf prefetch --
// round 13's +32 VGPR prefetch blew the 256-reg/wave budget: VGPR 104->128, scratch
// spill -> FETCH 133MB->1.14GB, scan 177->464us). Tail = round-13's validated
// per-query candidate lists + fused atomic-free rescore_final (saved ~50us vs r12).

#define DDIM 256
#define QTILE 128
#define STSZ 8192      // centroids per strip (8 strips)
#define QCAP 48        // candidate groups per query
#define F16_MINN 6.103515625e-5f

typedef __attribute__((ext_vector_type(8))) _Float16 half8;
typedef __attribute__((ext_vector_type(4))) _Float16 half4;
typedef __attribute__((ext_vector_type(4))) float f32x4;

__device__ __forceinline__ void gl_lds16(const void* g, void* l) {
  __builtin_amdgcn_global_load_lds((const __attribute__((address_space(1))) void*)g,
                                   (__attribute__((address_space(3))) void*)l, 16, 0, 0);
}

// exact order-preserving float -> uint key (finite floats; matches f32 <)
__device__ __forceinline__ unsigned fkey(float d) {
  unsigned ud = __float_as_uint(d);
  return ud ^ (((int)ud < 0) ? 0xFFFFFFFFu : 0x80000000u);
}

// ---------------- ctl init: [32]=cmax_sq bits ----------------
__global__ void initctl_kernel(unsigned* __restrict__ ctl) {
  if (threadIdx.x < 64) ctl[threadIdx.x] = 0u;
}

// ---------------- centroid split + c_sq fused (one wave = one 256-elem row) --------
__global__ __launch_bounds__(256) void splitc_kernel(const float* __restrict__ in,
                                                     _Float16* __restrict__ o0,
                                                     float* __restrict__ c_sq) {
  int i = blockIdx.x * 256 + threadIdx.x;   // 4-elem chunk id; wave = one row
  int lane = (int)threadIdx.x & 63;
  float4 v = ((const float4*)in)[i];
  float vv[4] = {v.x, v.y, v.z, v.w};
  half4 h0;
#pragma unroll
  for (int e = 0; e < 4; ++e)
    h0[e] = (fabsf(vv[e]) < F16_MINN) ? (_Float16)0.f : (_Float16)vv[e];
  *(half4*)(o0 + (size_t)i * 4) = h0;
  float s = fmaf(v.x, v.x, fmaf(v.y, v.y, fmaf(v.z, v.z, v.w * v.w)));
#pragma unroll
  for (int off = 32; off > 0; off >>= 1) s += __shfl_down(s, off, 64);
  if (lane == 0) c_sq[i >> 6] = s;
}

// ---------------- x split: hi part only ----------------
__global__ __launch_bounds__(256) void splitx_kernel(const float* __restrict__ in,
                                                     _Float16* __restrict__ o0, int n4) {
  int i = blockIdx.x * 256 + threadIdx.x;
  if (i >= n4) return;
  float4 v = ((const float4*)in)[i];
  float vv[4] = {v.x, v.y, v.z, v.w};
  half4 h0;
#pragma unroll
  for (int e = 0; e < 4; ++e)
    h0[e] = (fabsf(vv[e]) < F16_MINN) ? (_Float16)0.f : (_Float16)vv[e];
  *(half4*)(o0 + (size_t)i * 4) = h0;
}

// ---------------- cmax: 2-stage max of c_sq, one atomic per block (64 total) --------
__global__ __launch_bounds__(256) void cmax_kernel(const float* __restrict__ c_sq,
                                                   unsigned* __restrict__ ctl) {
  __shared__ float red[4];
  int t = blockIdx.x * 256 + (int)threadIdx.x;
  float4 v = ((const float4*)c_sq)[t];
  float m = fmaxf(fmaxf(v.x, v.y), fmaxf(v.z, v.w));
#pragma unroll
  for (int off = 32; off > 0; off >>= 1) m = fmaxf(m, __shfl_down(m, off, 64));
  int lane = (int)threadIdx.x & 63, w = (int)threadIdx.x >> 6;
  if (lane == 0) red[w] = m;
  __syncthreads();
  if (threadIdx.x == 0) {
    m = fmaxf(fmaxf(red[0], red[1]), fmaxf(red[2], red[3]));
    atomicMax(&ctl[32], __float_as_uint(m));
  }
}

// ---------------- scan: 1-term f16 MFMA (centroids=M rows), min per (q,32c-group) ----
// ROUND-12 VERBATIM (validated 177us / MfmaUtil 33 / no spill). No prefetch.
__global__ __launch_bounds__(512, 2) void scan_kernel(
    const _Float16* __restrict__ x0, const _Float16* __restrict__ c0,
    const float* __restrict__ c_sq, float* __restrict__ dm) {
  __shared__ __align__(16) _Float16 As0[32768];   // 64 KiB

  const int qb = blockIdx.x, kc = blockIdx.y;
  const int tid = (int)threadIdx.x;
  const int lane = tid & 63, w = tid >> 6;
  const int col = lane & 15, quad = lane >> 4;
  const int qrow0 = qb * QTILE;

#pragma unroll
  for (int i = 0; i < 8; ++i) {
    int u = i * 512 + tid;                 // 0..4095 (16B chunks)
    int kt = u >> 9, q = (u >> 7) & 3, r = u & 127;
    gl_lds16(x0 + (size_t)(qrow0 + r) * DDIM + kt * 32 + q * 8, As0 + (size_t)u * 8);
  }
  __syncthreads();   // only barrier

  for (int ct = 0; ct < STSZ / 512; ++ct) {
    const int cbase = kc * STSZ + ct * 512 + w * 64;   // wave-private 64-c slice
    f32x4 acc[4][8];                                    // [cm][qn]
#pragma unroll
    for (int cm = 0; cm < 4; ++cm)
#pragma unroll
      for (int qn = 0; qn < 8; ++qn) acc[cm][qn] = (f32x4)0.0f;

#pragma unroll 2
    for (int kt = 0; kt < 8; ++kt) {
      const int k0 = kt * 32;
      half8 cf[4];
#pragma unroll
      for (int cm = 0; cm < 4; ++cm)
        cf[cm] = *(const half8*)(c0 + (size_t)(cbase + cm * 16 + col) * DDIM + k0 + quad * 8);
#pragma unroll
      for (int qn = 0; qn < 8; ++qn) {
        half8 qf = *(const half8*)(As0 + (((kt * 4 + quad) * QTILE) + qn * 16 + col) * 8);
#pragma unroll
        for (int cm = 0; cm < 4; ++cm)
          acc[cm][qn] = __builtin_amdgcn_mfma_f32_16x16x32_f16(cf[cm], qf, acc[cm][qn], 0, 0, 0);
      }
    }

    // epilogue: d = cs - 2*dot; min over 32 centroids (2 cm-tiles: in-lane rg + quad xor)
    f32x4 csv[4];
#pragma unroll
    for (int cm = 0; cm < 4; ++cm)
      csv[cm] = *(const f32x4*)(c_sq + cbase + cm * 16 + quad * 4);
#pragma unroll
    for (int h = 0; h < 2; ++h) {
      const int grp = kc * 256 + ct * 16 + w * 2 + h;
      float* dmg = dm + (size_t)grp * 4096 + qrow0;
#pragma unroll
      for (int qn = 0; qn < 8; ++qn) {
        float mq = INFINITY;
#pragma unroll
        for (int c2 = 0; c2 < 2; ++c2) {
          int cm = h * 2 + c2;
#pragma unroll
          for (int rg = 0; rg < 4; ++rg)
            mq = fminf(mq, fmaf(-2.0f, acc[cm][qn][rg], csv[cm][rg]));
        }
        mq = fminf(mq, __shfl_xor(mq, 16, 64));
        mq = fminf(mq, __shfl_xor(mq, 32, 64));
        if (quad == 0) dmg[qn * 16 + col] = mq;         // 16 lanes, 64 B dense
      }
    }
  }
}

// ---------------- pmin: partial column-min of dm ----------------
__global__ __launch_bounds__(256) void pmin_kernel(const float* __restrict__ dm,
                                                   float* __restrict__ pm) {
  int qc = blockIdx.x & 15, gc = blockIdx.x >> 4;
  int q = qc * 256 + (int)threadIdx.x;
  float m = INFINITY;
  for (int g = gc * 128; g < gc * 128 + 128; ++g)
    m = fminf(m, dm[(size_t)g * 4096 + q]);
  pm[gc * 4096 + q] = m;
}

// ---------------- tq: per-query threshold + cnt zero ----------------
__global__ __launch_bounds__(256) void tq_kernel(const float* __restrict__ pm,
                                                 const float* __restrict__ x,
                                                 const unsigned* __restrict__ ctl,
                                                 float* __restrict__ T,
                                                 unsigned* __restrict__ cnt) {
  int q = blockIdx.x * 256 + (int)threadIdx.x;
  float M = INFINITY;
#pragma unroll
  for (int i = 0; i < 16; ++i) M = fminf(M, pm[i * 4096 + q]);
  float xsq = 0.f;
  const float4* xr = (const float4*)(x + (size_t)q * DDIM);
#pragma unroll 8
  for (int i = 0; i < 64; ++i) {
    float4 v = xr[i];
    xsq = fmaf(v.x, v.x, fmaf(v.y, v.y, fmaf(v.z, v.z, fmaf(v.w, v.w, xsq))));
  }
  float cmaxsq = __uint_as_float(ctl[32]);
  // rigorous 1-term f16 bound ~2^-9 ||x|| ||c||max; margin = 4x bound + 1.0 slack
  T[q] = M + 0.0078125f * sqrtf(xsq * cmaxsq) + 1.0f;
  cnt[q] = 0u;
}

// ---------------- emit: per-query candidate group lists (distributed atomics) --------
__global__ __launch_bounds__(256) void emit_kernel(const float* __restrict__ dm,
                                                   const float* __restrict__ T,
                                                   unsigned short* __restrict__ cand,
                                                   unsigned* __restrict__ cnt) {
  int qc = blockIdx.x & 15, gc = blockIdx.x >> 4;
  int q = qc * 256 + (int)threadIdx.x;
  float t = T[q];
  for (int g = gc * 128; g < gc * 128 + 128; ++g)
    if (dm[(size_t)g * 4096 + q] <= t) {
      unsigned slot = atomicAdd(&cnt[q], 1u);   // 4096 distinct counters, ~2 ops each
      if (slot < QCAP) cand[(size_t)q * QCAP + slot] = (unsigned short)g;
    }
}

// ---------------- rescore+final: wave per query, atomic-free ----------------
__global__ __launch_bounds__(256) void rescore_final_kernel(
    const unsigned short* __restrict__ cand, const unsigned* __restrict__ cnt,
    const float* __restrict__ x, const float* __restrict__ cent,
    const float* __restrict__ c_sq, float* __restrict__ out) {
  int q = blockIdx.x * 4 + ((int)threadIdx.x >> 6);
  int lane = (int)threadIdx.x & 63;
  unsigned n = cnt[q];
  unsigned long long best = 0xFFFFFFFFFFFFFFFFull;
  if (n >= 1 && n <= QCAP) {
    int dh = (lane & 1) * 128;
    const float4* xr = (const float4*)(x + (size_t)q * DDIM + dh);
    for (unsigned sl = 0; sl < n; ++sl) {
      int g = (int)cand[(size_t)q * QCAP + sl];
      int c = g * 32 + (lane >> 1);
      const float4* cr = (const float4*)(cent + (size_t)c * DDIM + dh);
      float s = 0.f;
#pragma unroll
      for (int i = 0; i < 32; ++i) {
        float4 a = xr[i], bb = cr[i];
        s = fmaf(a.x, bb.x, fmaf(a.y, bb.y, fmaf(a.z, bb.z, fmaf(a.w, bb.w, s))));
      }
      s += __shfl_xor(s, 1, 64);
      float d = (lane & 1) ? INFINITY : fmaf(-2.0f, s, c_sq[c]);
      unsigned long long pkv = ((unsigned long long)fkey(d) << 32) | (unsigned)c;
      if (pkv < best) best = pkv;
    }
  } else {
    // safety net: exact argmin over all 65536 (overflow / empty; should never trigger)
    const float4* xr = (const float4*)(x + (size_t)q * DDIM);
    for (int c = lane; c < 65536; c += 64) {
      const float4* cr = (const float4*)(cent + (size_t)c * DDIM);
      float s = 0.f;
#pragma unroll 16
      for (int i = 0; i < 64; ++i) {
        float4 a = xr[i], bb = cr[i];
        s = fmaf(a.x, bb.x, fmaf(a.y, bb.y, fmaf(a.z, bb.z, fmaf(a.w, bb.w, s))));
      }
      float d = fmaf(-2.0f, s, c_sq[c]);
      unsigned long long pkv = ((unsigned long long)fkey(d) << 32) | (unsigned)c;
      if (pkv < best) best = pkv;
    }
  }
#pragma unroll
  for (int off = 1; off < 64; off <<= 1) {
    unsigned long long o = __shfl_xor(best, off, 64);
    if (o < best) best = o;
  }
  int idx = (int)(unsigned)(best & 0xFFFFFFFFu);
  float4 v = ((const float4*)cent)[(size_t)idx * 64 + lane];
  ((float4*)out)[(size_t)q * 64 + lane] = v;
  if (lane == 0) out[(size_t)4096 * DDIM + q] = (float)idx;
}

extern "C" void kernel_launch(void* const* d_in, const int* in_sizes, int n_in,
                              void* d_out, int out_size, void* d_ws, size_t ws_size,
                              hipStream_t stream) {
  const float* x    = (const float*)d_in[1];   // [4096,256]
  const float* cent = (const float*)d_in[2];   // [65536,256]
  float* out = (float*)d_out;
  char* ws = (char*)d_ws;

  const size_t OFF_C0   = 0;           // 33,554,432  f16 hi(centroids)
  const size_t OFF_X0   = 33554432;    //  2,097,152  f16 hi(x)
  const size_t OFF_CSQ  = 35651584;    //    262,144
  const size_t OFF_CTL  = 35913728;    //        256
  const size_t OFF_DM   = 35913984;    // 33,554,432  f32[2048][4096]
  const size_t OFF_PM   = 69468416;    //    262,144  f32[16][4096]
  const size_t OFF_T    = 69730560;    //     16,384
  const size_t OFF_CNT  = 69746944;    //     16,384  u32[4096]
  const size_t OFF_CAND = 69763328;    //    393,216  u16[4096][48]
  const size_t NEED     = 72089600;    // proven available since round 2
  if (ws_size < NEED) return;

  _Float16* c0 = (_Float16*)(ws + OFF_C0);
  _Float16* x0 = (_Float16*)(ws + OFF_X0);
  float* c_sq = (float*)(ws + OFF_CSQ);
  unsigned* ctl = (unsigned*)(ws + OFF_CTL);
  float* dm = (float*)(ws + OFF_DM);
  float* pm = (float*)(ws + OFF_PM);
  float* T  = (float*)(ws + OFF_T);
  unsigned* cnt = (unsigned*)(ws + OFF_CNT);
  unsigned short* cand = (unsigned short*)(ws + OFF_CAND);

  initctl_kernel<<<1, 64, 0, stream>>>(ctl);
  splitc_kernel<<<16384, 256, 0, stream>>>(cent, c0, c_sq);
  splitx_kernel<<<1024, 256, 0, stream>>>(x, x0, 4096 * 256 / 4);
  cmax_kernel<<<64, 256, 0, stream>>>(c_sq, ctl);
  scan_kernel<<<dim3(32, 8), 512, 0, stream>>>(x0, c0, c_sq, dm);
  pmin_kernel<<<256, 256, 0, stream>>>(dm, pm);
  tq_kernel<<<16, 256, 0, stream>>>(pm, x, ctl, T, cnt);
  emit_kernel<<<256, 256, 0, stream>>>(dm, T, cand, cnt);
  rescore_final_kernel<<<1024, 256, 0, stream>>>(cand, cnt, x, cent, c_sq, out);
}